// Round 2
// baseline (600.175 us; speedup 1.0000x reference)
//
#include <hip/hip_runtime.h>
#include <cmath>

// Problem constants (B_SZ=2, L=2048, D=1024, N=16)
#define D_DIM 1024
#define N_DIM 16
#define KTOT  2049          // 2*D + 1 (concat axis)

typedef float v4f __attribute__((ext_vector_type(4)));

// ---------------------------------------------------------------------------
// One block (256 thr = 4 waves) per (b,l) token.
// Phase 1 (projection):
//   wave 0: B rows 0..7  (+ s_delta)   -> LDS
//   wave 1: B rows 8..15               -> LDS
//   wave 2: C rows 0..7                -> out[.., k=2048, 0..7]  (direct)
//   wave 3: C rows 8..15               -> out[.., k=2048, 8..15] (direct)
// Phase 2 (expansion): thread = (dloc = tid>>2, n4 = tid&3), loops 16 chunks
//   of d. Per chunk the wave stores two contiguous-1KB nontemporal dwordx4
//   streams (A_bar at k=d, deltaB_x at k=D+d). All transcendentals inline:
//   v_exp_f32 + v_rcp_f32 + branchless small-|dA| series (no libcalls).
// ---------------------------------------------------------------------------
__global__ __launch_bounds__(256, 4) void fused_ssm_kernel(
    const float* __restrict__ x, const float* __restrict__ W_b,
    const float* __restrict__ W_c, const float* __restrict__ W_delta,
    const float* __restrict__ A, const float* __restrict__ delta_param,
    float* __restrict__ out)
{
    const int bl   = blockIdx.x;
    const int tid  = threadIdx.x;
    const int wave = tid >> 6;
    const int lane = tid & 63;

    __shared__ float sB[17];   // B[0..15], sd at [16]

    const float* xrow = x + (size_t)bl * D_DIM;

    // ---------------- Phase 1: projections ----------------
    const float* Wbase = (wave < 2) ? W_b : W_c;
    const int rowbase  = (wave & 1) * 8;

    float acc[8] = {0.f,0.f,0.f,0.f,0.f,0.f,0.f,0.f};
    float sd = 0.f;

    #pragma unroll
    for (int i = 0; i < 4; ++i) {           // 4 iters x 64 lanes x float4 = 1024
        const int d = (i << 8) + (lane << 2);
        const v4f xv = *(const v4f*)(xrow + d);
        #pragma unroll
        for (int r = 0; r < 8; ++r) {
            const v4f wv = *(const v4f*)(Wbase + (size_t)(rowbase + r) * D_DIM + d);
            acc[r] = fmaf(xv.x, wv.x, acc[r]);
            acc[r] = fmaf(xv.y, wv.y, acc[r]);
            acc[r] = fmaf(xv.z, wv.z, acc[r]);
            acc[r] = fmaf(xv.w, wv.w, acc[r]);
        }
        if (wave == 0) {
            const v4f wd = *(const v4f*)(W_delta + d);
            sd = fmaf(xv.x, wd.x, sd);
            sd = fmaf(xv.y, wd.y, sd);
            sd = fmaf(xv.z, wd.z, sd);
            sd = fmaf(xv.w, wd.w, sd);
        }
    }

    // 64-lane xor-shuffle reduction (leaves the full sum in every lane)
    #pragma unroll
    for (int r = 0; r < 8; ++r) {
        #pragma unroll
        for (int m = 32; m >= 1; m >>= 1)
            acc[r] += __shfl_xor(acc[r], m, 64);
    }
    if (wave == 0) {
        #pragma unroll
        for (int m = 32; m >= 1; m >>= 1)
            sd += __shfl_xor(sd, m, 64);
    }

    if (lane == 0) {
        if (wave == 0) {
            #pragma unroll
            for (int r = 0; r < 8; ++r) sB[r] = acc[r];
            sB[16] = sd;
        } else if (wave == 1) {
            #pragma unroll
            for (int r = 0; r < 8; ++r) sB[8 + r] = acc[r];
        } else {
            // C straight into the k = 2*D slot of the output
            float* dst = out + ((size_t)bl * KTOT + 2 * D_DIM) * N_DIM + rowbase;
            #pragma unroll
            for (int r = 0; r < 8; ++r) dst[r] = acc[r];
        }
    }
    __syncthreads();

    // ---------------- Phase 2: expansion ----------------
    const int n4   = tid & 3;
    const int dloc = tid >> 2;
    const v4f   Bv  = *(const v4f*)(sB + (n4 << 2));
    const float sdv = sB[16];
    const size_t tokbase = (size_t)bl * KTOT * N_DIM;
    const float LOG2E = 1.44269504088896340736f;

    #pragma unroll 4
    for (int chunk = 0; chunk < 16; ++chunk) {
        const int d = (chunk << 6) + dloc;
        const float dp = delta_param[d];
        const v4f   Av = *(const v4f*)(A + (size_t)d * N_DIM + (n4 << 2));
        const float xv = xrow[d];

        // Delta = softplus(sd + delta_param[d]) — stable, inline
        const float z  = sdv + dp;
        const float ez = __builtin_amdgcn_exp2f(-fabsf(z) * LOG2E);
        const float Delta = fmaxf(z, 0.0f) +
                            __builtin_amdgcn_logf(1.0f + ez) * 0.69314718055994530942f;
        const float dx = Delta * xv;

        v4f Abar, dbx;
        #pragma unroll
        for (int i = 0; i < 4; ++i) {
            const float dA = Delta * Av[i];
            const float ex = __builtin_amdgcn_exp2f(dA * LOG2E);   // exp(dA)
            const float em = ex - 1.0f;
            // ratio = expm1(dA)/dA ; series for small |dA| (cancellation-safe)
            const float r_big   = em * __builtin_amdgcn_rcpf(dA);
            const float r_small = fmaf(dA, fmaf(dA, 0.16666667f, 0.5f), 1.0f);
            const float ratio   = (fabsf(dA) < 0.03125f) ? r_small : r_big;
            Abar[i] = ex;
            dbx[i]  = ratio * Bv[i] * dx;
        }

        const size_t base = tokbase + (size_t)d * N_DIM + (n4 << 2);
        __builtin_nontemporal_store(Abar, (v4f*)(out + base));
        __builtin_nontemporal_store(dbx,  (v4f*)(out + base + (size_t)D_DIM * N_DIM));
    }
}

extern "C" void kernel_launch(void* const* d_in, const int* in_sizes, int n_in,
                              void* d_out, int out_size, void* d_ws, size_t ws_size,
                              hipStream_t stream)
{
    const float* x           = (const float*)d_in[0];
    const float* W_b         = (const float*)d_in[1];
    const float* W_c         = (const float*)d_in[2];
    const float* W_delta     = (const float*)d_in[3];
    const float* A           = (const float*)d_in[4];
    const float* delta_param = (const float*)d_in[5];
    float* out = (float*)d_out;

    const int BL = in_sizes[0] / D_DIM;   // 4096 tokens

    fused_ssm_kernel<<<BL, 256, 0, stream>>>(x, W_b, W_c, W_delta, A, delta_param, out);
}